// Round 1
// baseline (424.862 us; speedup 1.0000x reference)
//
#include <hip/hip_runtime.h>

#define CI 32
#define CO 16
#define DIN 32

// LDS layouts (both padded for conflict-freedom):
//   xs[lid][ci]  : lid = ld*16 + lh*4 + lw (4x4x4 input cube), stride 33
//                  compute-read banks: (lid*33 + ci)%32 = (lid+ci)%32 -> 4 distinct ci per
//                  instruction (8 apart) => conflict-free
//   ws[k][co][ci]: k = kd*9+kh*3+kw, stride 33 rows
//                  compute-read banks: (16k + co + ci)%32, co 0..15 x ci {c,c+8,c+16,c+24}
//                  => exactly 2-way aliasing (free, m136)
// Total LDS: 64*33*4 + 27*16*33*4 = 8448 + 57024 = 65472 B (< 64 KiB static limit, 2 blocks/CU)

template <int PD, int PH, int PW>
__device__ __forceinline__ float phase_max(float (*xs)[33], float (*ws)[CO][33],
                                           int cig, int co) {
  constexpr int TD = PD ? 2 : 1, TH = PH ? 2 : 1, TW = PW ? 2 : 1;
  constexpr int LD = 3 + PD, LH = 3 + PH, LW = 3 + PW;

  float acc[27];
#pragma unroll
  for (int m = 0; m < 27; ++m) acc[m] = 0.f;

  for (int c8 = 0; c8 < 8; ++c8) {
    const int ci = cig * 8 + c8;

    // weights for this (ci, co): one scalar per tap, reused across 27 positions
    float wt[TD][TH][TW];
#pragma unroll
    for (int td = 0; td < TD; ++td) {
      const int kd = PD ? (td ? 2 : 0) : 1;
#pragma unroll
      for (int th = 0; th < TH; ++th) {
        const int kh = PH ? (th ? 2 : 0) : 1;
#pragma unroll
        for (int tw = 0; tw < TW; ++tw) {
          const int kw = PW ? (tw ? 2 : 0) : 1;
          wt[td][th][tw] = ws[kd * 9 + kh * 3 + kw][co][ci];
        }
      }
    }

    // x slice for this ci: LD x LH x LW values, broadcast across the 16 co-lanes
    float xv[LD][LH][LW];
#pragma unroll
    for (int d = 0; d < LD; ++d)
#pragma unroll
      for (int h = 0; h < LH; ++h)
#pragma unroll
        for (int w = 0; w < LW; ++w)
          xv[d][h][w] = xs[d * 16 + h * 4 + w][ci];

    // accumulate all 27 window positions of this phase
#pragma unroll
    for (int md = 0; md < 3; ++md)
#pragma unroll
      for (int mh = 0; mh < 3; ++mh)
#pragma unroll
        for (int mw = 0; mw < 3; ++mw) {
          float a = acc[(md * 3 + mh) * 3 + mw];
#pragma unroll
          for (int td = 0; td < TD; ++td) {
            const int dd = PD ? (td ? 0 : 1) : 0;  // kd=0 -> id=m+1 ; kd=2 -> id=m
#pragma unroll
            for (int th = 0; th < TH; ++th) {
              const int dh = PH ? (th ? 0 : 1) : 0;
#pragma unroll
              for (int tw = 0; tw < TW; ++tw) {
                const int dw = PW ? (tw ? 0 : 1) : 0;
                a = fmaf(xv[md + dd][mh + dh][mw + dw], wt[td][th][tw], a);
              }
            }
          }
          acc[(md * 3 + mh) * 3 + mw] = a;
        }
  }

  // reduce partial ci-sums across the 4 ci-groups (lanes differ in bits 4..5),
  // then max over this phase's 27 window positions
  float pm = -3.4e38f;
#pragma unroll
  for (int m = 0; m < 27; ++m) {
    float v = acc[m];
    v += __shfl_xor(v, 16, 64);
    v += __shfl_xor(v, 32, 64);
    pm = fmaxf(pm, v);
  }
  return pm;
}

__global__ __launch_bounds__(256) void fused_ctpool_kernel(
    const float* __restrict__ x, const float* __restrict__ W,
    const float* __restrict__ b, float* __restrict__ out) {
  __shared__ float xs[64][33];
  __shared__ float ws[27][CO][33];

  const int t = threadIdx.x;
  const int blk = blockIdx.x;  // 0..7999 = n*1000 + od*100 + oh*10 + ow
  const int n = blk / 1000;
  const int r = blk % 1000;
  const int od = r / 100;
  const int oh = (r / 10) % 10;
  const int ow = r % 10;

  // ---- stage weights: W[ci][co][kd][kh][kw] flat = (ci*16+co)*27 + k
  for (int i = t; i < CI * CO * 27; i += 256) {
    const int ci = i / (CO * 27);
    const int rem = i - ci * (CO * 27);
    const int co = rem / 27;
    const int k = rem - co * 27;
    ws[k][co][ci] = W[i];
  }

  // ---- stage x cube: 32 ci x 4x4x4 starting at (3od, 3oh, 3ow); always in-bounds
  {
    const float* xn = x + (size_t)n * (CI * DIN * DIN * DIN);
    const int d0 = 3 * od, h0 = 3 * oh, w0 = 3 * ow;
    for (int i = t; i < CI * 64; i += 256) {
      const int ci = i >> 6;
      const int lid = i & 63;
      const int ld = lid >> 4, lh = (lid >> 2) & 3, lw = lid & 3;
      xs[lid][ci] = xn[((ci * DIN + (d0 + ld)) * DIN + (h0 + lh)) * DIN + (w0 + lw)];
    }
  }
  __syncthreads();

  // wave -> 2 parity phases (paired to balance tap counts: 1+8, 2+4, 2+4, 2+4)
  const int wv = t >> 6;
  const int lane = t & 63;
  const int cig = lane >> 4;  // ci group: ci in [8*cig, 8*cig+8)
  const int co = lane & 15;

  float rmax;
  switch (wv) {
    case 0:
      rmax = fmaxf(phase_max<0, 0, 0>(xs, ws, cig, co),
                   phase_max<1, 1, 1>(xs, ws, cig, co));
      break;
    case 1:
      rmax = fmaxf(phase_max<0, 0, 1>(xs, ws, cig, co),
                   phase_max<0, 1, 1>(xs, ws, cig, co));
      break;
    case 2:
      rmax = fmaxf(phase_max<0, 1, 0>(xs, ws, cig, co),
                   phase_max<1, 0, 1>(xs, ws, cig, co));
      break;
    default:
      rmax = fmaxf(phase_max<1, 0, 0>(xs, ws, cig, co),
                   phase_max<1, 1, 0>(xs, ws, cig, co));
      break;
  }

  __syncthreads();  // everyone done reading xs; reuse its storage for reduction
  float* red = &xs[0][0];
  if (lane < 16) red[wv * 16 + co] = rmax;  // cig==0 lanes hold fully-reduced values
  __syncthreads();

  if (t == 0) {
    float s = 0.f;
    for (int c = 0; c < 16; ++c) {
      const float v =
          fmaxf(fmaxf(red[c], red[16 + c]), fmaxf(red[32 + c], red[48 + c]));
      s += v + b[c];
    }
    out[blk] = s;
  }
}

extern "C" void kernel_launch(void* const* d_in, const int* in_sizes, int n_in,
                              void* d_out, int out_size, void* d_ws, size_t ws_size,
                              hipStream_t stream) {
  const float* x = (const float*)d_in[0];   // 8*32*32*32*32
  const float* W = (const float*)d_in[1];   // 32*16*3*3*3
  const float* b = (const float*)d_in[2];   // 16
  float* out = (float*)d_out;               // 8000 floats
  fused_ctpool_kernel<<<dim3(8000), dim3(256), 0, stream>>>(x, W, b, out);
}

// Round 2
// 98.279 us; speedup vs baseline: 4.3230x; 4.3230x over previous
//
#include <hip/hip_runtime.h>

typedef __bf16 bf16;
typedef __bf16 bf16x8 __attribute__((ext_vector_type(8)));
typedef float f32x4 __attribute__((ext_vector_type(4)));

// ---------------- LDS x-slab layout ----------------
// xs[id 4][ih pad 5 (use 4)][iw pad 17 (use 16)][ci pad 40 (use 32)]  (bf16)
// row = 40 bf16 = 80 B (16B-aligned, so ds_read_b128 of 8 ci is aligned).
// dword bank steps: iw:+20, ih:+20, id:+4 (mod 32)  -> ~2-3-way max on A-reads.
#define CI_STRIDE 40
#define IW_STRIDE (CI_STRIDE)          // per +1 in iw (bf16 units)
#define IH_STRIDE (17 * CI_STRIDE)     // 680
#define ID_STRIDE (5 * 17 * CI_STRIDE) // 3400
#define XS_ELEMS (4 * ID_STRIDE)       // 13600 bf16 = 27200 B

// Pre-transpose W (32ci,16co,27tap fp32) into B-fragment order (bf16):
// flat o = ((tap*4 + quad)*16 + co)*8 + j   with ci = quad*8 + j
__global__ void transpose_w_kernel(const float* __restrict__ W, bf16* __restrict__ Wt) {
  int o = blockIdx.x * 256 + threadIdx.x;
  if (o < 27 * 512) {
    int j = o & 7, co = (o >> 3) & 15, q = (o >> 7) & 3, tap = o >> 9;
    int ci = q * 8 + j;
    Wt[o] = (bf16)W[(ci * 16 + co) * 27 + tap];
  }
}

__global__ __launch_bounds__(128) void fused_mfma_kernel(
    const float* __restrict__ x, const bf16* __restrict__ Wt,
    const float* __restrict__ b, float* __restrict__ out) {
  __shared__ __align__(16) bf16 xs[XS_ELEMS];
  __shared__ float red[5][2][16];

  const int t = threadIdx.x;
  const int lane = t & 63;
  const int wv = t >> 6;  // 0..1
  const int co = lane & 15;
  const int quad = lane >> 4;

  const int blk = blockIdx.x;      // 1600 = 800 slabs x 2 halves
  const int nodoh = blk >> 1;      // n*100 + od*10 + oh
  const int half = blk & 1;        // ow in [5*half, 5*half+5)
  const int n = nodoh / 100;
  const int od = (nodoh / 10) % 10;
  const int oh = nodoh % 10;

  // ---- B fragments: 27 taps, registers for the whole kernel
  bf16x8 bfrag[27];
  {
    const bf16x8* wp = (const bf16x8*)Wt;
#pragma unroll
    for (int tap = 0; tap < 27; ++tap)
      bfrag[tap] = wp[(tap * 4 + quad) * 16 + co];  // coalesced dwordx4, L2-hot
  }

  // ---- stage x slab: x[n][ci][3od+ld][3oh+lh][15*half + w], w in 0..15
  {
    const float* xn = x + (size_t)n * (32 * 32768) + (3 * od) * 1024 + (3 * oh) * 32 + 15 * half;
    for (int i = t; i < 512 * 16; i += 128) {
      int w = i & 15;
      int row = i >> 4;  // ci*16 + ld*4 + lh
      int ci = row >> 4, ld = (row >> 2) & 3, lh = row & 3;
      float v = xn[ci * 32768 + ld * 1024 + lh * 32 + w];
      xs[(size_t)ld * ID_STRIDE + lh * IH_STRIDE + w * IW_STRIDE + ci] = (bf16)v;
    }
  }
  __syncthreads();

  // ---- 10 tasks = 5 windows x 2 M-tiles; wave wv takes tasks wv, wv+2, ...
  for (int i = 0; i < 5; ++i) {
    const int tau = wv + 2 * i;
    const int w5 = tau >> 1;    // window within slab (ow = 5*half + w5)
    const int tb = (tau & 1) * 16;  // tile base row (positions tb..tb+15)

    // per-lane A base address: position = tb + (lane&15), clamped
    int pos = tb + (lane & 15);
    if (pos > 26) pos = 26;  // rows >=27 are garbage; masked in epilogue
    const int md = pos / 9;
    const int rem = pos - md * 9;
    const int mh = rem / 3;
    const int mw = rem - mh * 3;
    const bf16* ap = xs + (size_t)md * ID_STRIDE + mh * IH_STRIDE +
                     (3 * w5 + mw) * IW_STRIDE + quad * 8;

    // 8 distinct A fragments (input offsets (dd,dh,dw) in {0,1}^3)
    bf16x8 af[8];
#pragma unroll
    for (int dd = 0; dd < 2; ++dd)
#pragma unroll
      for (int dh = 0; dh < 2; ++dh)
#pragma unroll
        for (int dw = 0; dw < 2; ++dw)
          af[dd * 4 + dh * 2 + dw] =
              *(const bf16x8*)(ap + dd * ID_STRIDE + dh * IH_STRIDE + dw * IW_STRIDE);

    float tmax = -3.4e38f;
    // 8 parity phases; tap (kd,kh,kw): kd=1 if pd==0 else {0,2}; dd=(kd==0)
#pragma unroll
    for (int pd = 0; pd < 2; ++pd)
#pragma unroll
      for (int ph = 0; ph < 2; ++ph)
#pragma unroll
        for (int pw = 0; pw < 2; ++pw) {
          f32x4 acc = {0.f, 0.f, 0.f, 0.f};
#pragma unroll
          for (int td = 0; td <= pd; ++td)
#pragma unroll
            for (int th = 0; th <= ph; ++th)
#pragma unroll
              for (int tw = 0; tw <= pw; ++tw) {
                const int kd = pd ? (td ? 2 : 0) : 1;
                const int kh = ph ? (th ? 2 : 0) : 1;
                const int kw = pw ? (tw ? 2 : 0) : 1;
                const int tap = kd * 9 + kh * 3 + kw;
                const int ai = ((kd == 0) ? 4 : 0) + ((kh == 0) ? 2 : 0) + ((kw == 0) ? 1 : 0);
                acc = __builtin_amdgcn_mfma_f32_16x16x32_bf16(af[ai], bfrag[tap], acc, 0, 0, 0);
              }
          // C/D: col = lane&15 (co), row = quad*4 + reg  [m89-verified]
#pragma unroll
          for (int r = 0; r < 4; ++r) {
            if (tb + quad * 4 + r < 27) tmax = fmaxf(tmax, acc[r]);
          }
        }

    // max across quads -> lanes 0..15 hold full tile-max for their co
    tmax = fmaxf(tmax, __shfl_xor(tmax, 16, 64));
    tmax = fmaxf(tmax, __shfl_xor(tmax, 32, 64));
    if (quad == 0) red[w5][tau & 1][co] = tmax;
  }
  __syncthreads();

  // ---- finish: combine tiles, add bias, sum over co, store
  if (t < 80) {
    const int w5 = t >> 4;   // wave0: w5 0..3 (all lanes), wave1 lanes 0..15: w5=4
    const int c = t & 15;
    float v = fmaxf(red[w5][0][c], red[w5][1][c]) + b[c];
    v += __shfl_xor(v, 1, 64);
    v += __shfl_xor(v, 2, 64);
    v += __shfl_xor(v, 4, 64);
    v += __shfl_xor(v, 8, 64);
    if (c == 0) out[nodoh * 10 + half * 5 + w5] = v;
  }
}

extern "C" void kernel_launch(void* const* d_in, const int* in_sizes, int n_in,
                              void* d_out, int out_size, void* d_ws, size_t ws_size,
                              hipStream_t stream) {
  const float* x = (const float*)d_in[0];  // 8*32*32*32*32 fp32
  const float* W = (const float*)d_in[1];  // 32*16*27 fp32
  const float* b = (const float*)d_in[2];  // 16 fp32
  float* out = (float*)d_out;              // 8000 fp32
  bf16* Wt = (bf16*)d_ws;                  // 13824 bf16 = 27648 B scratch

  transpose_w_kernel<<<dim3(54), dim3(256), 0, stream>>>(W, Wt);
  fused_mfma_kernel<<<dim3(1600), dim3(128), 0, stream>>>(x, Wt, b, out);
}

// Round 3
// 92.186 us; speedup vs baseline: 4.6087x; 1.0661x over previous
//
#include <hip/hip_runtime.h>

typedef __bf16 bf16;
typedef __bf16 bf16x8 __attribute__((ext_vector_type(8)));
typedef float f32x4 __attribute__((ext_vector_type(4)));

// LDS x-slab: [ld 4][lh 4 (pad 5)][w 32 (pad 33)][ci 32 (pad 40)]  (bf16)
// ci-row = 40 bf16 = 80 B (16B-aligned); all strides 16B-aligned for b128.
#define W_STRIDE 40
#define H_STRIDE (33 * W_STRIDE)   // 1320
#define D_STRIDE (5 * H_STRIDE)    // 6600
#define XS_ELEMS (4 * D_STRIDE)    // 26400 bf16 = 52800 B

// W (32ci,16co,27tap fp32) -> B-fragment order bf16:
// o = ((tap*4 + quad)*16 + co)*8 + j, ci = quad*8 + j
__global__ void transpose_w_kernel(const float* __restrict__ W, bf16* __restrict__ Wt) {
  int o = blockIdx.x * 256 + threadIdx.x;
  if (o < 27 * 512) {
    int j = o & 7, co = (o >> 3) & 15, q = (o >> 7) & 3, tap = o >> 9;
    Wt[o] = (bf16)W[((q * 8 + j) * 16 + co) * 27 + tap];
  }
}

__global__ __launch_bounds__(256) void fused_mfma_kernel(
    const float* __restrict__ x, const bf16* __restrict__ Wt,
    const float* __restrict__ b, float* __restrict__ out) {
  __shared__ __align__(16) bf16 xs[XS_ELEMS];
  __shared__ float red[10][2][16];

  const int t = threadIdx.x;
  const int lane = t & 63;
  const int wv = t >> 6;  // 0..3
  const int co = lane & 15;
  const int quad = lane >> 4;

  const int blk = blockIdx.x;  // 800 = n*100 + od*10 + oh
  const int n = blk / 100;
  const int od = (blk / 10) % 10;
  const int oh = blk % 10;

  // ---- B fragments: 27 taps in registers for the whole kernel (L2-hot dwordx4)
  bf16x8 bfrag[27];
  {
    const bf16x8* wp = (const bf16x8*)Wt;
#pragma unroll
    for (int tap = 0; tap < 27; ++tap)
      bfrag[tap] = wp[(tap * 4 + quad) * 16 + co];
  }

  // ---- stage x slab: x[n][ci][3od+ld][3oh+lh][w 0..31] -> xs[ld][lh][w][ci]
  // per iter: 8-ci gather (each load coalesced across 32 consecutive-w lanes),
  // one ds_write_b128 (lane w-stride 80 B -> 8 lanes cover all 32 banks once).
  {
    const float* xn = x + (size_t)n * (32 * 32768) + (3 * od) * 1024 + (3 * oh) * 32;
#pragma unroll 2
    for (int it = 0; it < 8; ++it) {
      const int flat = it * 256 + t;  // 0..2047
      const int w = flat & 31;
      const int row = flat >> 5;      // 0..63
      const int cig = row & 3;        // 8 ci per gather
      const int lh = (row >> 2) & 3;
      const int ld = row >> 4;
      const float* g = xn + (size_t)(cig * 8) * 32768 + ld * 1024 + lh * 32 + w;
      bf16x8 pk;
#pragma unroll
      for (int j = 0; j < 8; ++j) pk[j] = (bf16)g[(size_t)j * 32768];
      *(bf16x8*)&xs[ld * D_STRIDE + lh * H_STRIDE + w * W_STRIDE + cig * 8] = pk;
    }
  }
  __syncthreads();

  // ---- 20 tasks = 10 windows x 2 M-tiles; wave-uniform tile (mask compile-uniform)
  const int tile = wv >> 1;  // 0,0,1,1
  const int tb = tile * 16;
  int pos = tb + (lane & 15);
  if (pos > 26) pos = 26;  // tile-1 garbage rows; excluded from max below
  const int md = pos / 9;
  const int mh = (pos / 3) % 3;
  const int mw = pos % 3;

  for (int i = 0; i < 5; ++i) {
    const int w10 = (wv & 1) * 5 + i;  // window ow
    const bf16* ap = xs + md * D_STRIDE + mh * H_STRIDE + (3 * w10 + mw) * W_STRIDE + quad * 8;

    // 8 distinct A fragments: input offsets (dd,dh,dw) in {0,1}^3
    bf16x8 af[8];
#pragma unroll
    for (int dd = 0; dd < 2; ++dd)
#pragma unroll
      for (int dh = 0; dh < 2; ++dh)
#pragma unroll
        for (int dw = 0; dw < 2; ++dw)
          af[dd * 4 + dh * 2 + dw] =
              *(const bf16x8*)(ap + dd * D_STRIDE + dh * H_STRIDE + dw * W_STRIDE);

    float tmax = -3.4e38f;
#pragma unroll
    for (int pd = 0; pd < 2; ++pd)
#pragma unroll
      for (int ph = 0; ph < 2; ++ph)
#pragma unroll
        for (int pw = 0; pw < 2; ++pw) {
          f32x4 acc = {0.f, 0.f, 0.f, 0.f};
#pragma unroll
          for (int td = 0; td <= pd; ++td)
#pragma unroll
            for (int th = 0; th <= ph; ++th)
#pragma unroll
              for (int tw = 0; tw <= pw; ++tw) {
                const int kd = pd ? (td ? 2 : 0) : 1;
                const int kh = ph ? (th ? 2 : 0) : 1;
                const int kw = pw ? (tw ? 2 : 0) : 1;
                const int ai = ((kd == 0) ? 4 : 0) + ((kh == 0) ? 2 : 0) + ((kw == 0) ? 1 : 0);
                acc = __builtin_amdgcn_mfma_f32_16x16x32_bf16(
                    af[ai], bfrag[kd * 9 + kh * 3 + kw], acc, 0, 0, 0);
              }
          // C/D: col = lane&15 (co), row = quad*4 + reg
          if (tile == 0) {  // rows 0..15 all valid (uniform branch)
#pragma unroll
            for (int r = 0; r < 4; ++r) tmax = fmaxf(tmax, acc[r]);
          } else {  // rows 16..31, valid iff < 27
#pragma unroll
            for (int r = 0; r < 4; ++r)
              if (16 + quad * 4 + r < 27) tmax = fmaxf(tmax, acc[r]);
          }
        }

    tmax = fmaxf(tmax, __shfl_xor(tmax, 16, 64));
    tmax = fmaxf(tmax, __shfl_xor(tmax, 32, 64));
    if (quad == 0) red[w10][tile][co] = tmax;
  }
  __syncthreads();

  // ---- combine tiles, add bias, sum over co, store (10 outputs/block)
  if (t < 160) {
    const int w10 = t >> 4;
    const int c = t & 15;
    float v = fmaxf(red[w10][0][c], red[w10][1][c]) + b[c];
    v += __shfl_xor(v, 1, 64);
    v += __shfl_xor(v, 2, 64);
    v += __shfl_xor(v, 4, 64);
    v += __shfl_xor(v, 8, 64);
    if (c == 0) out[blk * 10 + w10] = v;
  }
}

extern "C" void kernel_launch(void* const* d_in, const int* in_sizes, int n_in,
                              void* d_out, int out_size, void* d_ws, size_t ws_size,
                              hipStream_t stream) {
  const float* x = (const float*)d_in[0];  // 8*32*32*32*32 fp32
  const float* W = (const float*)d_in[1];  // 32*16*27 fp32
  const float* b = (const float*)d_in[2];  // 16 fp32
  float* out = (float*)d_out;              // 8000 fp32
  bf16* Wt = (bf16*)d_ws;                  // 13824 bf16 = 27648 B scratch

  transpose_w_kernel<<<dim3(54), dim3(256), 0, stream>>>(W, Wt);
  fused_mfma_kernel<<<dim3(800), dim3(256), 0, stream>>>(x, Wt, b, out);
}